// Round 3
// baseline (1192.937 us; speedup 1.0000x reference)
//
#include <hip/hip_runtime.h>

#define HH 512
#define WW 512
#define CIN 3
#define COUT 32
#define NB 16

typedef float f4 __attribute__((ext_vector_type(4)));

// One block = one (batch, output-channel, 32-row slab).
// Block: 256 flat threads; per pass covers 2 full rows (128 thr * 4 px each);
// 16 passes walk the slab top->bottom, so each block emits ONE LINEAR 64 KB
// write stream (fill-like), never hopping between o-planes. This is the
// decisive test of the "fragmented write streams" theory: all previous
// variants hopped 32 planes per thread and all measured the same ~223 us.
//
// Weights: the block's single o -> 24 taps s_load'ed once into SGPRs, used
// directly as v_fmac scalar operands. Center tap folded as -sum(neighbors)
// (3 uniform values) + bias. No LDS, no __syncthreads.
//
// Reads re-fetched once per o (32x amplification) but input is 48 MB,
// L3-resident; blockIdx.x = o keeps the 32 sharers dispatch-adjacent.
// Grid: (32, 16, 16) = (o, slab, b).
__global__ __launch_bounds__(256)
void pointconv_kernel(const float* __restrict__ x,
                      const float* __restrict__ Wg,
                      const float* __restrict__ bias,
                      float* __restrict__ out) {
    const int o    = blockIdx.x;   // 0..31 output channel
    const int slab = blockIdx.y;   // 0..15, 32 rows each
    const int b    = blockIdx.z;   // 0..15 batch

    const float* wo = Wg + o * 24;          // uniform -> s_load into SGPRs
    // Folded center taps: -sum of the 8 neighbor weights, per channel.
    float cneg0 = 0.f, cneg1 = 0.f, cneg2 = 0.f;
    #pragma unroll
    for (int k = 0; k < 8; ++k) {
        cneg0 -= wo[k * 3 + 0];
        cneg1 -= wo[k * 3 + 1];
        cneg2 -= wo[k * 3 + 2];
    }
    const float bv = bias[o];

    const int tid  = threadIdx.x;
    const int rsub = tid >> 7;           // 0..1 : row within the 2-row pass
    const int col  = (tid & 127) * 4;    // 0..508

    // COORDS k -> (row i, col j) within the 3x3 window (center excluded).
    const int TI[8] = {0, 1, 2, 0, 2, 0, 1, 2};
    const int TJ[8] = {0, 0, 0, 1, 1, 2, 2, 2};

    const float* xb   = x + (size_t)b * CIN * HH * WW;
    float*       outp = out + (((size_t)b * COUT + o) * HH) * WW;

    #pragma unroll 1
    for (int p = 0; p < 16; ++p) {
        const int y = slab * 32 + p * 2 + rsub;

        // Stage 3 channels x 3 rows x 6 cols (col-1 .. col+4) in registers.
        float v[3][3][6];
        #pragma unroll
        for (int c = 0; c < 3; ++c) {
            const float* xc = xb + (size_t)c * HH * WW;
            #pragma unroll
            for (int r = 0; r < 3; ++r) {
                const int yy = y + r - 1;
                const bool rowok = (yy >= 0) && (yy < HH);
                const float* row = xc + (ptrdiff_t)yy * WW;
                f4 mid;
                if (rowok) {
                    mid = *(const f4*)(row + col);
                } else {
                    mid = (f4){0.f, 0.f, 0.f, 0.f};
                }
                v[c][r][1] = mid.x; v[c][r][2] = mid.y;
                v[c][r][3] = mid.z; v[c][r][4] = mid.w;
                v[c][r][0] = (rowok && col > 0)        ? row[col - 1] : 0.f;
                v[c][r][5] = (rowok && col + 4 < WW)   ? row[col + 4] : 0.f;
            }
        }

        float a0 = bv, a1 = bv, a2 = bv, a3 = bv;
        #pragma unroll
        for (int k = 0; k < 8; ++k) {
            const int ty = TI[k], tx = TJ[k];
            #pragma unroll
            for (int c = 0; c < 3; ++c) {
                const float w = wo[k * 3 + c];   // SGPR operand
                a0 += w * v[c][ty][0 + tx];
                a1 += w * v[c][ty][1 + tx];
                a2 += w * v[c][ty][2 + tx];
                a3 += w * v[c][ty][3 + tx];
            }
        }
        // Center taps (cols 1..4 of the window).
        a0 += cneg0 * v[0][1][1]; a1 += cneg0 * v[0][1][2];
        a2 += cneg0 * v[0][1][3]; a3 += cneg0 * v[0][1][4];
        a0 += cneg1 * v[1][1][1]; a1 += cneg1 * v[1][1][2];
        a2 += cneg1 * v[1][1][3]; a3 += cneg1 * v[1][1][4];
        a0 += cneg2 * v[2][1][1]; a1 += cneg2 * v[2][1][2];
        a2 += cneg2 * v[2][1][3]; a3 += cneg2 * v[2][1][4];

        *(f4*)(outp + (size_t)y * WW + col) = (f4){a0, a1, a2, a3};
    }
}

extern "C" void kernel_launch(void* const* d_in, const int* in_sizes, int n_in,
                              void* d_out, int out_size, void* d_ws, size_t ws_size,
                              hipStream_t stream) {
    const float* x    = (const float*)d_in[0];
    const float* Wg   = (const float*)d_in[1];
    const float* bias = (const float*)d_in[2];
    float* out = (float*)d_out;

    dim3 block(256, 1, 1);
    dim3 grid(32, 16, 16);   // (o, slab, batch)
    hipLaunchKernelGGL(pointconv_kernel, grid, block, 0, stream, x, Wg, bias, out);
}